// Round 10
// baseline (226.848 us; speedup 1.0000x reference)
//
#include <hip/hip_runtime.h>

// R4: device-scope grid barriers cost O(100us) on MI355X. Block-local only.
// R6: gather needs >=3000 blocks (M=16 tiles -> 3125).
// R7: keep gather hot loop lean; slot-reduce prologues only in few-block kernels.
// R8: sage gather ~80% memory-stall; 12.8MB table > 4MB/XCD L2.
// R9: dispatch boundaries are NOT ~12us (removing one was neutral). Remaining
//     cost is in-kernel. This round: 16-wide masked gather chunks -> 1 latency
//     round for ~90% of nodes (deg<=16), 2x per-wave MLP.

#define NN 50000
#define NE 600000
#define FIN 64
#define FHID 128
#define BN_EPS 1e-5f
#define CAP 64
#define NSLOT 32

typedef __attribute__((ext_vector_type(8))) short short8;
typedef __attribute__((ext_vector_type(4))) float f32x4;

// ---- bf16 helpers (finite inputs; RNE) ----
__device__ __forceinline__ unsigned short f2bf(float f) {
  unsigned u = __float_as_uint(f);
  return (unsigned short)((u + 0x7FFFu + ((u >> 16) & 1u)) >> 16);
}
__device__ __forceinline__ float bfs(unsigned short u) {
  return __uint_as_float(((unsigned)u) << 16);
}
__device__ __forceinline__ float bflo(unsigned v) { return __uint_as_float(v << 16); }
__device__ __forceinline__ float bfhi(unsigned v) { return __uint_as_float(v & 0xFFFF0000u); }
__device__ __forceinline__ unsigned pk2(float lo, float hi) {
  return (unsigned)f2bf(lo) | ((unsigned)f2bf(hi) << 16);
}

// ---- build_all: edge scatter || weight pack || x->bf16 convert -------------
// Wp layout: ((n*NKS+ks)*64+lane)*8+kk ; k=ks*32+(lane>>4)*8+kk ; col=n*16+(lane&15)
__global__ __launch_bounds__(256) void build_all(
    const int* __restrict__ src, const int* __restrict__ dst,
    const float* __restrict__ x, int* __restrict__ cnt, int* __restrict__ csr,
    const float* __restrict__ W1, const float* __restrict__ Wl,
    const float* __restrict__ Wr, short* __restrict__ Wp1,
    short* __restrict__ Wp2, ushort4* __restrict__ xsr, int nbE4, int nbW) {
  int tid = threadIdx.x;
  int b = blockIdx.x;
  if (b < nbE4) {
    int e4 = b * 256 + tid;  // 4 edges/thread; NE % 4 == 0
    if (e4 * 4 < NE) {
      int4 d4 = ((const int4*)dst)[e4];
      int4 s4 = ((const int4*)src)[e4];
      int p;
      p = atomicAdd(&cnt[d4.x], 1); if (p < CAP) csr[(size_t)d4.x * CAP + p] = s4.x;
      p = atomicAdd(&cnt[d4.y], 1); if (p < CAP) csr[(size_t)d4.y * CAP + p] = s4.y;
      p = atomicAdd(&cnt[d4.z], 1); if (p < CAP) csr[(size_t)d4.z * CAP + p] = s4.z;
      p = atomicAdd(&cnt[d4.w], 1); if (p < CAP) csr[(size_t)d4.w * CAP + p] = s4.w;
    }
  } else if (b < nbE4 + nbW) {
    int widx = (b - nbE4) * 256 + tid;  // 0..40959
    if (widx < 8192) {  // Wp1: NKS=2, source W1[64][128]
      int kk = widx & 7, lane = (widx >> 3) & 63, ks = (widx >> 9) & 1,
          n = widx >> 10;
      int q = lane >> 4, r = lane & 15;
      int k = ks * 32 + q * 8 + kk, col = n * 16 + r;
      Wp1[widx] = (short)f2bf(W1[k * 128 + col]);
    } else if (widx < 8192 + 32768) {  // Wp2: NKS=8, source Wl|Wr [128][128]
      int w2 = widx - 8192;
      int kk = w2 & 7, lane = (w2 >> 3) & 63, ks = (w2 >> 9) & 7, n = w2 >> 12;
      int q = lane >> 4, r = lane & 15;
      int k = ks * 32 + q * 8 + kk, col = n * 16 + r;
      float wv = (k < 128) ? Wl[k * 128 + col] : Wr[(k - 128) * 128 + col];
      Wp2[w2] = (short)f2bf(wv);
    }
  } else {
    int i = (b - nbE4 - nbW) * 256 + tid;  // float4 idx; 3125 blocks exact
    float4 v = ((const float4*)x)[i];
    xsr[i] = make_ushort4(f2bf(v.x), f2bf(v.y), f2bf(v.z), f2bf(v.w));
  }
}

// ---- GCN block (M=16): 16-wide masked gather (per-edge dis fma) -> LDS -----
// -> K=64 MFMA. hb RAW (bias only, pre-BN).
__global__ __launch_bounds__(256) void gcn_block(
    const unsigned short* __restrict__ xs, const int* __restrict__ csr,
    const int* __restrict__ cnt, const short* __restrict__ Wp1,
    const float* __restrict__ b1, unsigned short* __restrict__ hb,
    float* __restrict__ sums1s, float* __restrict__ sumsq1s) {
  __shared__ unsigned short xaS[16][72];  // 144B row stride (16B aligned)
  __shared__ float lsum[128], lsq[128];
  int tid = threadIdx.x;
  if (tid < 128) { lsum[tid] = 0.f; lsq[tid] = 0.f; }
  int row_base = blockIdx.x * 16;  // 3125*16 = 50000 exact
  int li = tid & 15, g = tid >> 4;
  int node = row_base + g;
  {
    int degr = cnt[node];
    int degc = min(degr, CAP);
    float di = rsqrtf((float)(degr + 1));
    ushort4 sv = *(const ushort4*)(xs + (size_t)node * FIN + li * 4);
    // acc = di*x_self + sum_e dis[s]*x_s ; output = di*acc
    float a0 = di * bfs(sv.x), a1 = di * bfs(sv.y);
    float a2 = di * bfs(sv.z), a3 = di * bfs(sv.w);
    float dis0 = rsqrtf((float)(cnt[0] + 1));
    ushort4 zv = *(const ushort4*)(xs + li * 4);  // row 0 (mask target)
    const int* cb = csr + (size_t)node * CAP;
    float padtot = 0.f;
    for (int e = 0; e < degc; e += 16) {
      int valid = degc - e;  // >=1
      int4 A = *(const int4*)(cb + e);
      int4 B = *(const int4*)(cb + e + 4);
      int4 C = *(const int4*)(cb + e + 8);
      int4 D = *(const int4*)(cb + e + 12);
      int i0 = (0 < valid) ? A.x : 0,  i1 = (1 < valid) ? A.y : 0;
      int i2 = (2 < valid) ? A.z : 0,  i3 = (3 < valid) ? A.w : 0;
      int i4_ = (4 < valid) ? B.x : 0, i5 = (5 < valid) ? B.y : 0;
      int i6 = (6 < valid) ? B.z : 0,  i7 = (7 < valid) ? B.w : 0;
      int i8 = (8 < valid) ? C.x : 0,  i9 = (9 < valid) ? C.y : 0;
      int iA = (10 < valid) ? C.z : 0, iB = (11 < valid) ? C.w : 0;
      int iC = (12 < valid) ? D.x : 0, iD = (13 < valid) ? D.y : 0;
      int iE = (14 < valid) ? D.z : 0, iF = (15 < valid) ? D.w : 0;
      float d0 = rsqrtf((float)(cnt[i0] + 1)), d1 = rsqrtf((float)(cnt[i1] + 1));
      float d2 = rsqrtf((float)(cnt[i2] + 1)), d3 = rsqrtf((float)(cnt[i3] + 1));
      float d4 = rsqrtf((float)(cnt[i4_] + 1)), d5 = rsqrtf((float)(cnt[i5] + 1));
      float d6 = rsqrtf((float)(cnt[i6] + 1)), d7 = rsqrtf((float)(cnt[i7] + 1));
      float d8 = rsqrtf((float)(cnt[i8] + 1)), d9 = rsqrtf((float)(cnt[i9] + 1));
      float dA = rsqrtf((float)(cnt[iA] + 1)), dB = rsqrtf((float)(cnt[iB] + 1));
      float dC = rsqrtf((float)(cnt[iC] + 1)), dD = rsqrtf((float)(cnt[iD] + 1));
      float dE = rsqrtf((float)(cnt[iE] + 1)), dF = rsqrtf((float)(cnt[iF] + 1));
      ushort4 v0 = *(const ushort4*)(xs + (size_t)i0 * FIN + li * 4);
      ushort4 v1 = *(const ushort4*)(xs + (size_t)i1 * FIN + li * 4);
      ushort4 v2 = *(const ushort4*)(xs + (size_t)i2 * FIN + li * 4);
      ushort4 v3 = *(const ushort4*)(xs + (size_t)i3 * FIN + li * 4);
      ushort4 v4 = *(const ushort4*)(xs + (size_t)i4_ * FIN + li * 4);
      ushort4 v5 = *(const ushort4*)(xs + (size_t)i5 * FIN + li * 4);
      ushort4 v6 = *(const ushort4*)(xs + (size_t)i6 * FIN + li * 4);
      ushort4 v7 = *(const ushort4*)(xs + (size_t)i7 * FIN + li * 4);
      ushort4 v8 = *(const ushort4*)(xs + (size_t)i8 * FIN + li * 4);
      ushort4 v9 = *(const ushort4*)(xs + (size_t)i9 * FIN + li * 4);
      ushort4 vA = *(const ushort4*)(xs + (size_t)iA * FIN + li * 4);
      ushort4 vB = *(const ushort4*)(xs + (size_t)iB * FIN + li * 4);
      ushort4 vC = *(const ushort4*)(xs + (size_t)iC * FIN + li * 4);
      ushort4 vD = *(const ushort4*)(xs + (size_t)iD * FIN + li * 4);
      ushort4 vE = *(const ushort4*)(xs + (size_t)iE * FIN + li * 4);
      ushort4 vF = *(const ushort4*)(xs + (size_t)iF * FIN + li * 4);
      a0 += d0 * bfs(v0.x); a1 += d0 * bfs(v0.y); a2 += d0 * bfs(v0.z); a3 += d0 * bfs(v0.w);
      a0 += d1 * bfs(v1.x); a1 += d1 * bfs(v1.y); a2 += d1 * bfs(v1.z); a3 += d1 * bfs(v1.w);
      a0 += d2 * bfs(v2.x); a1 += d2 * bfs(v2.y); a2 += d2 * bfs(v2.z); a3 += d2 * bfs(v2.w);
      a0 += d3 * bfs(v3.x); a1 += d3 * bfs(v3.y); a2 += d3 * bfs(v3.z); a3 += d3 * bfs(v3.w);
      a0 += d4 * bfs(v4.x); a1 += d4 * bfs(v4.y); a2 += d4 * bfs(v4.z); a3 += d4 * bfs(v4.w);
      a0 += d5 * bfs(v5.x); a1 += d5 * bfs(v5.y); a2 += d5 * bfs(v5.z); a3 += d5 * bfs(v5.w);
      a0 += d6 * bfs(v6.x); a1 += d6 * bfs(v6.y); a2 += d6 * bfs(v6.z); a3 += d6 * bfs(v6.w);
      a0 += d7 * bfs(v7.x); a1 += d7 * bfs(v7.y); a2 += d7 * bfs(v7.z); a3 += d7 * bfs(v7.w);
      a0 += d8 * bfs(v8.x); a1 += d8 * bfs(v8.y); a2 += d8 * bfs(v8.z); a3 += d8 * bfs(v8.w);
      a0 += d9 * bfs(v9.x); a1 += d9 * bfs(v9.y); a2 += d9 * bfs(v9.z); a3 += d9 * bfs(v9.w);
      a0 += dA * bfs(vA.x); a1 += dA * bfs(vA.y); a2 += dA * bfs(vA.z); a3 += dA * bfs(vA.w);
      a0 += dB * bfs(vB.x); a1 += dB * bfs(vB.y); a2 += dB * bfs(vB.z); a3 += dB * bfs(vB.w);
      a0 += dC * bfs(vC.x); a1 += dC * bfs(vC.y); a2 += dC * bfs(vC.z); a3 += dC * bfs(vC.w);
      a0 += dD * bfs(vD.x); a1 += dD * bfs(vD.y); a2 += dD * bfs(vD.z); a3 += dD * bfs(vD.w);
      a0 += dE * bfs(vE.x); a1 += dE * bfs(vE.y); a2 += dE * bfs(vE.z); a3 += dE * bfs(vE.w);
      a0 += dF * bfs(vF.x); a1 += dF * bfs(vF.y); a2 += dF * bfs(vF.z); a3 += dF * bfs(vF.w);
      padtot += (float)(16 - min(valid, 16));
    }
    // masked lanes gathered row 0 scaled by dis0
    float pc = padtot * dis0;
    a0 -= pc * bfs(zv.x); a1 -= pc * bfs(zv.y);
    a2 -= pc * bfs(zv.z); a3 -= pc * bfs(zv.w);
    *(ushort4*)(&xaS[g][li * 4]) = make_ushort4(
        f2bf(di * a0), f2bf(di * a1), f2bf(di * a2), f2bf(di * a3));
  }
  __syncthreads();

  int lane = tid & 63, w = tid >> 6, r = lane & 15, q = lane >> 4;
  int n0 = w * 2, n1 = w * 2 + 1;
  short8 af0 = *(const short8*)(&xaS[r][q * 8]);
  short8 af1 = *(const short8*)(&xaS[r][32 + q * 8]);
  f32x4 acc0 = (f32x4){0.f, 0.f, 0.f, 0.f}, acc1 = acc0;
  acc0 = __builtin_amdgcn_mfma_f32_16x16x32_bf16(
      af0, *(const short8*)(Wp1 + ((size_t)(n0 * 2 + 0) * 64 + lane) * 8), acc0, 0, 0, 0);
  acc1 = __builtin_amdgcn_mfma_f32_16x16x32_bf16(
      af0, *(const short8*)(Wp1 + ((size_t)(n1 * 2 + 0) * 64 + lane) * 8), acc1, 0, 0, 0);
  acc0 = __builtin_amdgcn_mfma_f32_16x16x32_bf16(
      af1, *(const short8*)(Wp1 + ((size_t)(n0 * 2 + 1) * 64 + lane) * 8), acc0, 0, 0, 0);
  acc1 = __builtin_amdgcn_mfma_f32_16x16x32_bf16(
      af1, *(const short8*)(Wp1 + ((size_t)(n1 * 2 + 1) * 64 + lane) * 8), acc1, 0, 0, 0);

  float b0 = b1[n0 * 16 + r], bb1 = b1[n1 * 16 + r];
  float cs0 = 0.f, cq0 = 0.f, cs1 = 0.f, cq1 = 0.f;
#pragma unroll
  for (int i = 0; i < 4; ++i) {
    int row = row_base + q * 4 + i;  // grid exact, always < NN
    float v0 = acc0[i] + b0;
    float v1 = acc1[i] + bb1;
    hb[(size_t)row * 128 + n0 * 16 + r] = f2bf(v0);
    hb[(size_t)row * 128 + n1 * 16 + r] = f2bf(v1);
    cs0 += v0; cq0 += v0 * v0;
    cs1 += v1; cq1 += v1 * v1;
  }
  atomicAdd(&lsum[n0 * 16 + r], cs0);
  atomicAdd(&lsq[n0 * 16 + r], cq0);
  atomicAdd(&lsum[n1 * 16 + r], cs1);
  atomicAdd(&lsq[n1 * 16 + r], cq1);
  __syncthreads();
  if (tid < 128) {
    int s = blockIdx.x & (NSLOT - 1);
    atomicAdd(&sums1s[s * 128 + tid], lsum[tid]);
    atomicAdd(&sumsq1s[s * 128 + tid], lsq[tid]);
  }
}

// ---- BN1 finalize (slot reduce once) + apply + ReLU, bf16 in-place ---------
__global__ __launch_bounds__(256) void bn_slot_apply_bf(
    unsigned* __restrict__ hb, const float* __restrict__ sums1s,
    const float* __restrict__ sumsq1s, const float* __restrict__ gamma,
    const float* __restrict__ beta) {
  __shared__ float sc[128], sh[128];
  int t = threadIdx.x;
  if (t < 128) {
    float ms = 0.f, vs = 0.f;
#pragma unroll
    for (int s = 0; s < NSLOT; ++s) {
      ms += sums1s[s * 128 + t];
      vs += sumsq1s[s * 128 + t];
    }
    float mean = ms * (1.0f / NN);
    float var = fmaxf(vs * (1.0f / NN) - mean * mean, 0.f);
    float sgm = gamma[t] * rsqrtf(var + BN_EPS);
    sc[t] = sgm;
    sh[t] = beta[t] - mean * sgm;
  }
  __syncthreads();
  for (int i = blockIdx.x * 256 + t; i < NN * FHID / 4; i += gridDim.x * 256) {
    uint2 v = ((uint2*)hb)[i];
    int c = (i & 31) * 4;
    float f0 = fmaxf(fmaf(bflo(v.x), sc[c + 0], sh[c + 0]), 0.f);
    float f1 = fmaxf(fmaf(bfhi(v.x), sc[c + 1], sh[c + 1]), 0.f);
    float f2 = fmaxf(fmaf(bflo(v.y), sc[c + 2], sh[c + 2]), 0.f);
    float f3 = fmaxf(fmaf(bfhi(v.y), sc[c + 3], sh[c + 3]), 0.f);
    v.x = pk2(f0, f1);
    v.y = pk2(f2, f3);
    ((uint2*)hb)[i] = v;
  }
}

// ---- SAGE block (M=16): 16-wide masked mean-agg of BN'd hb -> K=256 MFMA ---
__device__ __forceinline__ void sacc(float* a, uint4 v) {
  a[0] += bflo(v.x); a[1] += bfhi(v.x);
  a[2] += bflo(v.y); a[3] += bfhi(v.y);
  a[4] += bflo(v.z); a[5] += bfhi(v.z);
  a[6] += bflo(v.w); a[7] += bfhi(v.w);
}

__global__ __launch_bounds__(256) void sage_block(
    const unsigned short* __restrict__ hb, const int* __restrict__ csr,
    const int* __restrict__ cnt, const short* __restrict__ Wp2,
    const float* __restrict__ bl, float* __restrict__ out,
    float* __restrict__ sums2s, float* __restrict__ sumsq2s) {
  __shared__ unsigned short nbS[16][136];  // 272B row stride (16B aligned)
  __shared__ float lsum[128], lsq[128];
  int tid = threadIdx.x;
  if (tid < 128) { lsum[tid] = 0.f; lsq[tid] = 0.f; }
  int row_base = blockIdx.x * 16;
  int li = tid & 15, g = tid >> 4;
  int node = row_base + g;
  const unsigned* hbu = (const unsigned*)hb;
  {
    int degr = cnt[node];
    int degc = min(degr, CAP);
    float a[8];
#pragma unroll
    for (int j = 0; j < 8; ++j) a[j] = 0.f;
    uint4 zv = *(const uint4*)(hbu + li * 4);  // BN'd row 0 (mask target)
    const int* cb = csr + (size_t)node * CAP;
    float padtot = 0.f;
    for (int e = 0; e < degc; e += 16) {
      int valid = degc - e;  // >=1
      int4 A = *(const int4*)(cb + e);
      int4 B = *(const int4*)(cb + e + 4);
      int4 C = *(const int4*)(cb + e + 8);
      int4 D = *(const int4*)(cb + e + 12);
      int i0 = (0 < valid) ? A.x : 0,  i1 = (1 < valid) ? A.y : 0;
      int i2 = (2 < valid) ? A.z : 0,  i3 = (3 < valid) ? A.w : 0;
      int i4_ = (4 < valid) ? B.x : 0, i5 = (5 < valid) ? B.y : 0;
      int i6 = (6 < valid) ? B.z : 0,  i7 = (7 < valid) ? B.w : 0;
      int i8 = (8 < valid) ? C.x : 0,  i9 = (9 < valid) ? C.y : 0;
      int iA = (10 < valid) ? C.z : 0, iB = (11 < valid) ? C.w : 0;
      int iC = (12 < valid) ? D.x : 0, iD = (13 < valid) ? D.y : 0;
      int iE = (14 < valid) ? D.z : 0, iF = (15 < valid) ? D.w : 0;
      uint4 v0 = *(const uint4*)(hbu + (size_t)i0 * 64 + li * 4);
      uint4 v1 = *(const uint4*)(hbu + (size_t)i1 * 64 + li * 4);
      uint4 v2 = *(const uint4*)(hbu + (size_t)i2 * 64 + li * 4);
      uint4 v3 = *(const uint4*)(hbu + (size_t)i3 * 64 + li * 4);
      uint4 v4 = *(const uint4*)(hbu + (size_t)i4_ * 64 + li * 4);
      uint4 v5 = *(const uint4*)(hbu + (size_t)i5 * 64 + li * 4);
      uint4 v6 = *(const uint4*)(hbu + (size_t)i6 * 64 + li * 4);
      uint4 v7 = *(const uint4*)(hbu + (size_t)i7 * 64 + li * 4);
      uint4 v8 = *(const uint4*)(hbu + (size_t)i8 * 64 + li * 4);
      uint4 v9 = *(const uint4*)(hbu + (size_t)i9 * 64 + li * 4);
      uint4 vA = *(const uint4*)(hbu + (size_t)iA * 64 + li * 4);
      uint4 vB = *(const uint4*)(hbu + (size_t)iB * 64 + li * 4);
      uint4 vC = *(const uint4*)(hbu + (size_t)iC * 64 + li * 4);
      uint4 vD = *(const uint4*)(hbu + (size_t)iD * 64 + li * 4);
      uint4 vE = *(const uint4*)(hbu + (size_t)iE * 64 + li * 4);
      uint4 vF = *(const uint4*)(hbu + (size_t)iF * 64 + li * 4);
      sacc(a, v0); sacc(a, v1); sacc(a, v2); sacc(a, v3);
      sacc(a, v4); sacc(a, v5); sacc(a, v6); sacc(a, v7);
      sacc(a, v8); sacc(a, v9); sacc(a, vA); sacc(a, vB);
      sacc(a, vC); sacc(a, vD); sacc(a, vE); sacc(a, vF);
      padtot += (float)(16 - min(valid, 16));
    }
    a[0] -= padtot * bflo(zv.x); a[1] -= padtot * bfhi(zv.x);
    a[2] -= padtot * bflo(zv.y); a[3] -= padtot * bfhi(zv.y);
    a[4] -= padtot * bflo(zv.z); a[5] -= padtot * bfhi(zv.z);
    a[6] -= padtot * bflo(zv.w); a[7] -= padtot * bfhi(zv.w);
    float inv = 1.0f / fmaxf((float)degr, 1.0f);
    uint4 o;
    o.x = pk2(a[0] * inv, a[1] * inv);
    o.y = pk2(a[2] * inv, a[3] * inv);
    o.z = pk2(a[4] * inv, a[5] * inv);
    o.w = pk2(a[6] * inv, a[7] * inv);
    *(uint4*)(&nbS[g][li * 8]) = o;
  }
  __syncthreads();

  int lane = tid & 63, w = tid >> 6, r = lane & 15, q = lane >> 4;
  int n0 = w * 2, n1 = w * 2 + 1;
  short8 af[8];
#pragma unroll
  for (int ks = 0; ks < 4; ++ks)
    af[ks] = *(const short8*)(&nbS[r][ks * 32 + q * 8]);
  int rowg = row_base + r;  // grid exact, always < NN
#pragma unroll
  for (int ks = 4; ks < 8; ++ks) {  // A2 = BN'd hb, direct read
    int kg = (ks - 4) * 32 + q * 8;
    af[ks] = *(const short8*)((const short*)hb + (size_t)rowg * 128 + kg);
  }
  f32x4 acc0 = (f32x4){0.f, 0.f, 0.f, 0.f}, acc1 = acc0;
#pragma unroll
  for (int ks = 0; ks < 8; ++ks) {
    acc0 = __builtin_amdgcn_mfma_f32_16x16x32_bf16(
        af[ks], *(const short8*)(Wp2 + ((size_t)(n0 * 8 + ks) * 64 + lane) * 8),
        acc0, 0, 0, 0);
    acc1 = __builtin_amdgcn_mfma_f32_16x16x32_bf16(
        af[ks], *(const short8*)(Wp2 + ((size_t)(n1 * 8 + ks) * 64 + lane) * 8),
        acc1, 0, 0, 0);
  }

  float b0 = bl[n0 * 16 + r], bb1 = bl[n1 * 16 + r];
  float cs0 = 0.f, cq0 = 0.f, cs1 = 0.f, cq1 = 0.f;
#pragma unroll
  for (int i = 0; i < 4; ++i) {
    int row = row_base + q * 4 + i;
    float v0 = acc0[i] + b0;
    float v1 = acc1[i] + bb1;
    out[(size_t)row * 128 + n0 * 16 + r] = v0;
    out[(size_t)row * 128 + n1 * 16 + r] = v1;
    cs0 += v0; cq0 += v0 * v0;
    cs1 += v1; cq1 += v1 * v1;
  }
  atomicAdd(&lsum[n0 * 16 + r], cs0);
  atomicAdd(&lsq[n0 * 16 + r], cq0);
  atomicAdd(&lsum[n1 * 16 + r], cs1);
  atomicAdd(&lsq[n1 * 16 + r], cq1);
  __syncthreads();
  if (tid < 128) {
    int s = blockIdx.x & (NSLOT - 1);
    atomicAdd(&sums2s[s * 128 + tid], lsum[tid]);
    atomicAdd(&sumsq2s[s * 128 + tid], lsq[tid]);
  }
}

// ---- BN2 finalize (slot reduce once) + apply + ReLU, fp32 in-place ---------
__global__ __launch_bounds__(256) void bn_slot_apply_f32(
    float* __restrict__ out, const float* __restrict__ sums2s,
    const float* __restrict__ sumsq2s, const float* __restrict__ gamma,
    const float* __restrict__ beta) {
  __shared__ float sc[128], sh[128];
  int t = threadIdx.x;
  if (t < 128) {
    float ms = 0.f, vs = 0.f;
#pragma unroll
    for (int s = 0; s < NSLOT; ++s) {
      ms += sums2s[s * 128 + t];
      vs += sumsq2s[s * 128 + t];
    }
    float mean = ms * (1.0f / NN);
    float var = fmaxf(vs * (1.0f / NN) - mean * mean, 0.f);
    float sgm = gamma[t] * rsqrtf(var + BN_EPS);
    sc[t] = sgm;
    sh[t] = beta[t] - mean * sgm;
  }
  __syncthreads();
  for (int i4 = blockIdx.x * 256 + t; i4 < NN * FHID / 4; i4 += gridDim.x * 256) {
    float4 v = ((const float4*)out)[i4];
    int f = (i4 & 31) * 4;
    v.x = fmaxf(fmaf(v.x, sc[f + 0], sh[f + 0]), 0.f);
    v.y = fmaxf(fmaf(v.y, sc[f + 1], sh[f + 1]), 0.f);
    v.z = fmaxf(fmaf(v.z, sc[f + 2], sh[f + 2]), 0.f);
    v.w = fmaxf(fmaf(v.w, sc[f + 3], sh[f + 3]), 0.f);
    ((float4*)out)[i4] = v;
  }
}

extern "C" void kernel_launch(void* const* d_in, const int* in_sizes, int n_in,
                              void* d_out, int out_size, void* d_ws, size_t ws_size,
                              hipStream_t stream) {
  const float* x   = (const float*)d_in[0];
  const int*   ei  = (const int*)d_in[1];
  const float* W1  = (const float*)d_in[2];
  const float* b1  = (const float*)d_in[3];
  const float* g1  = (const float*)d_in[4];
  const float* be1 = (const float*)d_in[5];
  const float* Wl  = (const float*)d_in[6];
  const float* bl  = (const float*)d_in[7];
  const float* Wr  = (const float*)d_in[8];
  const float* g2  = (const float*)d_in[9];
  const float* be2 = (const float*)d_in[10];
  const int* srcp = ei;
  const int* dstp = ei + NE;

  char* w = (char*)d_ws;
  auto alloc = [&](size_t bytes) {
    char* p = w;
    w += (bytes + 255) & ~(size_t)255;
    return p;
  };
  // single zeroed zone: cnt[NN] | slotted stats 4 x [32][128]
  size_t zbytes = ((size_t)NN + 4 * NSLOT * 128) * 4;
  char* zz = (char*)alloc(zbytes);
  int*   cnt   = (int*)zz;
  float* stats = (float*)(cnt + NN);
  float* sums1s = stats,                     *sumsq1s = stats + NSLOT * 128;
  float* sums2s = stats + 2 * NSLOT * 128,   *sumsq2s = stats + 3 * NSLOT * 128;

  int*   csr = (int*)alloc((size_t)NN * CAP * 4);  // 12.8 MB strided buckets
  unsigned short* xs = (unsigned short*)alloc((size_t)NN * FIN * 2);
  unsigned short* hb = (unsigned short*)alloc((size_t)NN * FHID * 2);
  short* Wp1 = (short*)alloc(8192 * 2);
  short* Wp2 = (short*)alloc(32768 * 2);

  hipMemsetAsync(zz, 0, zbytes, stream);

  int nbE4 = (NE / 4 + 255) / 256;        // 586 edge blocks
  int nbW  = (8192 + 32768 + 255) / 256;  // 160 weight-pack blocks
  int nbX  = NN * FIN / 4 / 256;          // 3125 x-convert blocks
  int nb16 = NN / 16;                     // 3125 fused agg+GEMM blocks

  // 1: CSR build || weight pack || x->bf16 (independent block ranges)
  build_all<<<nbE4 + nbW + nbX, 256, 0, stream>>>(
      srcp, dstp, x, cnt, csr, W1, Wl, Wr, Wp1, Wp2, (ushort4*)xs, nbE4, nbW);
  // 2: GCN 16-wide masked gather + K=64 MFMA -> hb + stats1
  gcn_block<<<nb16, 256, 0, stream>>>(xs, csr, cnt, Wp1, b1, hb, sums1s, sumsq1s);
  // 3: BN1 finalize + apply + ReLU in place on hb
  bn_slot_apply_bf<<<512, 256, 0, stream>>>((unsigned*)hb, sums1s, sumsq1s, g1, be1);
  // 4: SAGE 16-wide masked mean-agg + K=256 MFMA -> fp32 out + stats2
  sage_block<<<nb16, 256, 0, stream>>>(hb, csr, cnt, Wp2, bl, (float*)d_out,
                                       sums2s, sumsq2s);
  // 5: BN2 finalize + apply + ReLU
  bn_slot_apply_f32<<<512, 256, 0, stream>>>((float*)d_out, sums2s, sumsq2s, g2, be2);
}

// Round 11
// 215.651 us; speedup vs baseline: 1.0519x; 1.0519x over previous
//
#include <hip/hip_runtime.h>

// R4: device-scope grid barriers cost O(100us) on MI355X. Block-local only.
// R6: gather needs >=3000 blocks (M=16 tiles -> 3125).
// R7: keep gather hot loop lean (plain adds); slot-reduce prologues only in
//     few-block kernels.
// R8: sage gather is ~80% memory-stall (12.8MB table > 4MB/XCD L2).
// R9/R10: boundary removal neutral; 16-wide chunks regress (masked-slot waste
//     + cndmask VALU). Gather is at LLC random-row service floor ~3 TB/s.
//     This version = R8's measured-best (215.0us) configuration, restored.

#define NN 50000
#define NE 600000
#define FIN 64
#define FHID 128
#define BN_EPS 1e-5f
#define CAP 64
#define NSLOT 32

typedef __attribute__((ext_vector_type(8))) short short8;
typedef __attribute__((ext_vector_type(4))) float f32x4;

// ---- bf16 helpers (finite inputs; RNE) ----
__device__ __forceinline__ unsigned short f2bf(float f) {
  unsigned u = __float_as_uint(f);
  return (unsigned short)((u + 0x7FFFu + ((u >> 16) & 1u)) >> 16);
}
__device__ __forceinline__ float bfs(unsigned short u) {
  return __uint_as_float(((unsigned)u) << 16);
}
__device__ __forceinline__ float bflo(unsigned v) { return __uint_as_float(v << 16); }
__device__ __forceinline__ float bfhi(unsigned v) { return __uint_as_float(v & 0xFFFF0000u); }
__device__ __forceinline__ unsigned pk2(float lo, float hi) {
  return (unsigned)f2bf(lo) | ((unsigned)f2bf(hi) << 16);
}

// -------- bucket CSR build + (spare blocks) pack weights to frag layout -----
// Wp layout: ((n*NKS+ks)*64+lane)*8+kk ; k=ks*32+(lane>>4)*8+kk ; col=n*16+(lane&15)
__global__ __launch_bounds__(256) void bucket_fill(
    const int* __restrict__ src, const int* __restrict__ dst,
    int* __restrict__ cnt, int* __restrict__ csr,
    const float* __restrict__ W1, const float* __restrict__ Wl,
    const float* __restrict__ Wr, short* __restrict__ Wp1,
    short* __restrict__ Wp2, int nbE4) {
  int tid = threadIdx.x;
  if ((int)blockIdx.x < nbE4) {
    int e4 = blockIdx.x * 256 + tid;  // 4 edges/thread; NE % 4 == 0
    if (e4 * 4 < NE) {
      int4 d4 = ((const int4*)dst)[e4];
      int4 s4 = ((const int4*)src)[e4];
      int p;
      p = atomicAdd(&cnt[d4.x], 1); if (p < CAP) csr[(size_t)d4.x * CAP + p] = s4.x;
      p = atomicAdd(&cnt[d4.y], 1); if (p < CAP) csr[(size_t)d4.y * CAP + p] = s4.y;
      p = atomicAdd(&cnt[d4.z], 1); if (p < CAP) csr[(size_t)d4.z * CAP + p] = s4.z;
      p = atomicAdd(&cnt[d4.w], 1); if (p < CAP) csr[(size_t)d4.w * CAP + p] = s4.w;
    }
  } else {
    int widx = (blockIdx.x - nbE4) * 256 + tid;  // 0..40959
    if (widx < 8192) {  // Wp1: NKS=2, source W1[64][128]
      int kk = widx & 7, lane = (widx >> 3) & 63, ks = (widx >> 9) & 1,
          n = widx >> 10;
      int q = lane >> 4, r = lane & 15;
      int k = ks * 32 + q * 8 + kk, col = n * 16 + r;
      Wp1[widx] = (short)f2bf(W1[k * 128 + col]);
    } else if (widx < 8192 + 32768) {  // Wp2: NKS=8, source Wl|Wr [128][128]
      int w2 = widx - 8192;
      int kk = w2 & 7, lane = (w2 >> 3) & 63, ks = (w2 >> 9) & 7, n = w2 >> 12;
      int q = lane >> 4, r = lane & 15;
      int k = ks * 32 + q * 8 + kk, col = n * 16 + r;
      float wv = (k < 128) ? Wl[k * 128 + col] : Wr[(k - 128) * 128 + col];
      Wp2[w2] = (short)f2bf(wv);
    }
  }
}

// ------- xs = dis[node]*x (fp32 -> bf16 prescale), fused bucket padding ------
__global__ __launch_bounds__(256) void scale_x(const float* __restrict__ x,
                                               const int* __restrict__ cnt,
                                               ushort4* __restrict__ xs,
                                               int* __restrict__ csr) {
  int i = blockIdx.x * 256 + threadIdx.x;  // float4 index; grid exact (800000)
  float4 v = ((const float4*)x)[i];
  int node = i >> 4;  // 16 float4 per 64-wide row
  float d = rsqrtf((float)(cnt[node] + 1));
  xs[i] = make_ushort4(f2bf(v.x * d), f2bf(v.y * d), f2bf(v.z * d), f2bf(v.w * d));
  if (i < NN) {
    int deg = min(cnt[i], CAP);
    int deg8 = (deg + 7) & ~7;
    int* cb = csr + (size_t)i * CAP;
    for (int p = deg; p < deg8; ++p) cb[p] = 0;
  }
}

__device__ __forceinline__ void gacc(float& a0, float& a1, float& a2, float& a3,
                                     ushort4 v) {
  a0 += bfs(v.x); a1 += bfs(v.y); a2 += bfs(v.z); a3 += bfs(v.w);
}

// ---- GCN block (M=16): 1 node per 16-lane group -> LDS -> K=64 MFMA --------
// hb output RAW (bias only, pre-BN). Stats into slotted partials.
__global__ __launch_bounds__(256) void gcn_block(
    const unsigned short* __restrict__ xs, const int* __restrict__ csr,
    const int* __restrict__ cnt, const short* __restrict__ Wp1,
    const float* __restrict__ b1, unsigned short* __restrict__ hb,
    float* __restrict__ sums1s, float* __restrict__ sumsq1s) {
  __shared__ unsigned short xaS[16][72];  // 144B row stride (16B aligned)
  __shared__ float lsum[128], lsq[128];
  int tid = threadIdx.x;
  if (tid < 128) { lsum[tid] = 0.f; lsq[tid] = 0.f; }
  int row_base = blockIdx.x * 16;  // 3125*16 = 50000 exact
  int li = tid & 15, g = tid >> 4;
  int node = row_base + g;
  {
    int degr = cnt[node];
    int deg = min(degr, CAP);
    int deg8 = (deg + 7) & ~7;
    float di = rsqrtf((float)(degr + 1));
    ushort4 sv = *(const ushort4*)(xs + (size_t)node * FIN + li * 4);
    float a0 = bfs(sv.x), a1 = bfs(sv.y), a2 = bfs(sv.z), a3 = bfs(sv.w);
    ushort4 zv = *(const ushort4*)(xs + li * 4);  // row 0 (pad target)
    const int* cb = csr + (size_t)node * CAP;
    int4 sA = *(const int4*)(cb);
    int4 sB = *(const int4*)(cb + 4);
    for (int e = 0; e < deg8; e += 8) {
      int pn = min(e + 8, CAP - 8);
      int4 nA = *(const int4*)(cb + pn);
      int4 nB = *(const int4*)(cb + pn + 4);
      ushort4 v0 = *(const ushort4*)(xs + (size_t)sA.x * FIN + li * 4);
      ushort4 v1 = *(const ushort4*)(xs + (size_t)sA.y * FIN + li * 4);
      ushort4 v2 = *(const ushort4*)(xs + (size_t)sA.z * FIN + li * 4);
      ushort4 v3 = *(const ushort4*)(xs + (size_t)sA.w * FIN + li * 4);
      ushort4 v4 = *(const ushort4*)(xs + (size_t)sB.x * FIN + li * 4);
      ushort4 v5 = *(const ushort4*)(xs + (size_t)sB.y * FIN + li * 4);
      ushort4 v6 = *(const ushort4*)(xs + (size_t)sB.z * FIN + li * 4);
      ushort4 v7 = *(const ushort4*)(xs + (size_t)sB.w * FIN + li * 4);
      gacc(a0, a1, a2, a3, v0); gacc(a0, a1, a2, a3, v1);
      gacc(a0, a1, a2, a3, v2); gacc(a0, a1, a2, a3, v3);
      gacc(a0, a1, a2, a3, v4); gacc(a0, a1, a2, a3, v5);
      gacc(a0, a1, a2, a3, v6); gacc(a0, a1, a2, a3, v7);
      sA = nA; sB = nB;
    }
    float pc = (float)(deg8 - deg);
    a0 -= pc * bfs(zv.x); a1 -= pc * bfs(zv.y);
    a2 -= pc * bfs(zv.z); a3 -= pc * bfs(zv.w);
    *(ushort4*)(&xaS[g][li * 4]) = make_ushort4(
        f2bf(di * a0), f2bf(di * a1), f2bf(di * a2), f2bf(di * a3));
  }
  __syncthreads();

  int lane = tid & 63, w = tid >> 6, r = lane & 15, q = lane >> 4;
  int n0 = w * 2, n1 = w * 2 + 1;
  short8 af0 = *(const short8*)(&xaS[r][q * 8]);
  short8 af1 = *(const short8*)(&xaS[r][32 + q * 8]);
  f32x4 acc0 = (f32x4){0.f, 0.f, 0.f, 0.f}, acc1 = acc0;
  acc0 = __builtin_amdgcn_mfma_f32_16x16x32_bf16(
      af0, *(const short8*)(Wp1 + ((size_t)(n0 * 2 + 0) * 64 + lane) * 8), acc0, 0, 0, 0);
  acc1 = __builtin_amdgcn_mfma_f32_16x16x32_bf16(
      af0, *(const short8*)(Wp1 + ((size_t)(n1 * 2 + 0) * 64 + lane) * 8), acc1, 0, 0, 0);
  acc0 = __builtin_amdgcn_mfma_f32_16x16x32_bf16(
      af1, *(const short8*)(Wp1 + ((size_t)(n0 * 2 + 1) * 64 + lane) * 8), acc0, 0, 0, 0);
  acc1 = __builtin_amdgcn_mfma_f32_16x16x32_bf16(
      af1, *(const short8*)(Wp1 + ((size_t)(n1 * 2 + 1) * 64 + lane) * 8), acc1, 0, 0, 0);

  float b0 = b1[n0 * 16 + r], bb1 = b1[n1 * 16 + r];
  float cs0 = 0.f, cq0 = 0.f, cs1 = 0.f, cq1 = 0.f;
#pragma unroll
  for (int i = 0; i < 4; ++i) {
    int row = row_base + q * 4 + i;  // grid exact, always < NN
    float v0 = acc0[i] + b0;
    float v1 = acc1[i] + bb1;
    hb[(size_t)row * 128 + n0 * 16 + r] = f2bf(v0);
    hb[(size_t)row * 128 + n1 * 16 + r] = f2bf(v1);
    cs0 += v0; cq0 += v0 * v0;
    cs1 += v1; cq1 += v1 * v1;
  }
  atomicAdd(&lsum[n0 * 16 + r], cs0);
  atomicAdd(&lsq[n0 * 16 + r], cq0);
  atomicAdd(&lsum[n1 * 16 + r], cs1);
  atomicAdd(&lsq[n1 * 16 + r], cq1);
  __syncthreads();
  if (tid < 128) {
    int s = blockIdx.x & (NSLOT - 1);
    atomicAdd(&sums1s[s * 128 + tid], lsum[tid]);
    atomicAdd(&sumsq1s[s * 128 + tid], lsq[tid]);
  }
}

// ---- BN1 finalize (slot reduce once) + apply + ReLU, bf16 in-place ---------
// grid-stride at 512 blocks: slot-reduce prologue runs 512x, not 6250x.
__global__ __launch_bounds__(256) void bn_slot_apply_bf(
    unsigned* __restrict__ hb, const float* __restrict__ sums1s,
    const float* __restrict__ sumsq1s, const float* __restrict__ gamma,
    const float* __restrict__ beta) {
  __shared__ float sc[128], sh[128];
  int t = threadIdx.x;
  if (t < 128) {
    float ms = 0.f, vs = 0.f;
#pragma unroll
    for (int s = 0; s < NSLOT; ++s) {
      ms += sums1s[s * 128 + t];
      vs += sumsq1s[s * 128 + t];
    }
    float mean = ms * (1.0f / NN);
    float var = fmaxf(vs * (1.0f / NN) - mean * mean, 0.f);
    float sgm = gamma[t] * rsqrtf(var + BN_EPS);
    sc[t] = sgm;
    sh[t] = beta[t] - mean * sgm;
  }
  __syncthreads();
  for (int i = blockIdx.x * 256 + t; i < NN * FHID / 4; i += gridDim.x * 256) {
    uint2 v = ((uint2*)hb)[i];
    int c = (i & 31) * 4;
    float f0 = fmaxf(fmaf(bflo(v.x), sc[c + 0], sh[c + 0]), 0.f);
    float f1 = fmaxf(fmaf(bfhi(v.x), sc[c + 1], sh[c + 1]), 0.f);
    float f2 = fmaxf(fmaf(bflo(v.y), sc[c + 2], sh[c + 2]), 0.f);
    float f3 = fmaxf(fmaf(bfhi(v.y), sc[c + 3], sh[c + 3]), 0.f);
    v.x = pk2(f0, f1);
    v.y = pk2(f2, f3);
    ((uint2*)hb)[i] = v;
  }
}

// ---- SAGE block (M=16): plain-add mean-agg of BN'd hb -> LDS -> K=256 MFMA -
__device__ __forceinline__ void sacc(float* a, uint4 v) {
  a[0] += bflo(v.x); a[1] += bfhi(v.x);
  a[2] += bflo(v.y); a[3] += bfhi(v.y);
  a[4] += bflo(v.z); a[5] += bfhi(v.z);
  a[6] += bflo(v.w); a[7] += bfhi(v.w);
}

__global__ __launch_bounds__(256) void sage_block(
    const unsigned short* __restrict__ hb, const int* __restrict__ csr,
    const int* __restrict__ cnt, const short* __restrict__ Wp2,
    const float* __restrict__ bl, float* __restrict__ out,
    float* __restrict__ sums2s, float* __restrict__ sumsq2s) {
  __shared__ unsigned short nbS[16][136];  // 272B row stride (16B aligned)
  __shared__ float lsum[128], lsq[128];
  int tid = threadIdx.x;
  if (tid < 128) { lsum[tid] = 0.f; lsq[tid] = 0.f; }
  int row_base = blockIdx.x * 16;
  int li = tid & 15, g = tid >> 4;
  int node = row_base + g;
  const unsigned* hbu = (const unsigned*)hb;
  {
    int degr = cnt[node];
    int deg = min(degr, CAP);
    int deg8 = (deg + 7) & ~7;
    float a[8];
#pragma unroll
    for (int j = 0; j < 8; ++j) a[j] = 0.f;
    uint4 zv = *(const uint4*)(hbu + li * 4);  // BN'd row 0 (pad target)
    const int* cb = csr + (size_t)node * CAP;
    int4 sA = *(const int4*)(cb);
    int4 sB = *(const int4*)(cb + 4);
    for (int e = 0; e < deg8; e += 8) {
      int pn = min(e + 8, CAP - 8);
      int4 nA = *(const int4*)(cb + pn);
      int4 nB = *(const int4*)(cb + pn + 4);
      uint4 v0 = *(const uint4*)(hbu + (size_t)sA.x * 64 + li * 4);
      uint4 v1 = *(const uint4*)(hbu + (size_t)sA.y * 64 + li * 4);
      uint4 v2 = *(const uint4*)(hbu + (size_t)sA.z * 64 + li * 4);
      uint4 v3 = *(const uint4*)(hbu + (size_t)sA.w * 64 + li * 4);
      uint4 v4 = *(const uint4*)(hbu + (size_t)sB.x * 64 + li * 4);
      uint4 v5 = *(const uint4*)(hbu + (size_t)sB.y * 64 + li * 4);
      uint4 v6 = *(const uint4*)(hbu + (size_t)sB.z * 64 + li * 4);
      uint4 v7 = *(const uint4*)(hbu + (size_t)sB.w * 64 + li * 4);
      sacc(a, v0); sacc(a, v1); sacc(a, v2); sacc(a, v3);
      sacc(a, v4); sacc(a, v5); sacc(a, v6); sacc(a, v7);
      sA = nA; sB = nB;
    }
    float pc = (float)(deg8 - deg);
    a[0] -= pc * bflo(zv.x); a[1] -= pc * bfhi(zv.x);
    a[2] -= pc * bflo(zv.y); a[3] -= pc * bfhi(zv.y);
    a[4] -= pc * bflo(zv.z); a[5] -= pc * bfhi(zv.z);
    a[6] -= pc * bflo(zv.w); a[7] -= pc * bfhi(zv.w);
    float inv = 1.0f / fmaxf((float)degr, 1.0f);
    uint4 o;
    o.x = pk2(a[0] * inv, a[1] * inv);
    o.y = pk2(a[2] * inv, a[3] * inv);
    o.z = pk2(a[4] * inv, a[5] * inv);
    o.w = pk2(a[6] * inv, a[7] * inv);
    *(uint4*)(&nbS[g][li * 8]) = o;
  }
  __syncthreads();

  int lane = tid & 63, w = tid >> 6, r = lane & 15, q = lane >> 4;
  int n0 = w * 2, n1 = w * 2 + 1;
  short8 af[8];
#pragma unroll
  for (int ks = 0; ks < 4; ++ks)
    af[ks] = *(const short8*)(&nbS[r][ks * 32 + q * 8]);
  int rowg = row_base + r;  // grid exact, always < NN
#pragma unroll
  for (int ks = 4; ks < 8; ++ks) {  // A2 = BN'd hb, direct read
    int kg = (ks - 4) * 32 + q * 8;
    af[ks] = *(const short8*)((const short*)hb + (size_t)rowg * 128 + kg);
  }
  f32x4 acc0 = (f32x4){0.f, 0.f, 0.f, 0.f}, acc1 = acc0;
#pragma unroll
  for (int ks = 0; ks < 8; ++ks) {
    acc0 = __builtin_amdgcn_mfma_f32_16x16x32_bf16(
        af[ks], *(const short8*)(Wp2 + ((size_t)(n0 * 8 + ks) * 64 + lane) * 8),
        acc0, 0, 0, 0);
    acc1 = __builtin_amdgcn_mfma_f32_16x16x32_bf16(
        af[ks], *(const short8*)(Wp2 + ((size_t)(n1 * 8 + ks) * 64 + lane) * 8),
        acc1, 0, 0, 0);
  }

  float b0 = bl[n0 * 16 + r], bb1 = bl[n1 * 16 + r];
  float cs0 = 0.f, cq0 = 0.f, cs1 = 0.f, cq1 = 0.f;
#pragma unroll
  for (int i = 0; i < 4; ++i) {
    int row = row_base + q * 4 + i;
    float v0 = acc0[i] + b0;
    float v1 = acc1[i] + bb1;
    out[(size_t)row * 128 + n0 * 16 + r] = v0;
    out[(size_t)row * 128 + n1 * 16 + r] = v1;
    cs0 += v0; cq0 += v0 * v0;
    cs1 += v1; cq1 += v1 * v1;
  }
  atomicAdd(&lsum[n0 * 16 + r], cs0);
  atomicAdd(&lsq[n0 * 16 + r], cq0);
  atomicAdd(&lsum[n1 * 16 + r], cs1);
  atomicAdd(&lsq[n1 * 16 + r], cq1);
  __syncthreads();
  if (tid < 128) {
    int s = blockIdx.x & (NSLOT - 1);
    atomicAdd(&sums2s[s * 128 + tid], lsum[tid]);
    atomicAdd(&sumsq2s[s * 128 + tid], lsq[tid]);
  }
}

// ---- BN2 finalize (slot reduce once) + apply + ReLU, fp32 in-place ---------
__global__ __launch_bounds__(256) void bn_slot_apply_f32(
    float* __restrict__ out, const float* __restrict__ sums2s,
    const float* __restrict__ sumsq2s, const float* __restrict__ gamma,
    const float* __restrict__ beta) {
  __shared__ float sc[128], sh[128];
  int t = threadIdx.x;
  if (t < 128) {
    float ms = 0.f, vs = 0.f;
#pragma unroll
    for (int s = 0; s < NSLOT; ++s) {
      ms += sums2s[s * 128 + t];
      vs += sumsq2s[s * 128 + t];
    }
    float mean = ms * (1.0f / NN);
    float var = fmaxf(vs * (1.0f / NN) - mean * mean, 0.f);
    float sgm = gamma[t] * rsqrtf(var + BN_EPS);
    sc[t] = sgm;
    sh[t] = beta[t] - mean * sgm;
  }
  __syncthreads();
  for (int i4 = blockIdx.x * 256 + t; i4 < NN * FHID / 4; i4 += gridDim.x * 256) {
    float4 v = ((const float4*)out)[i4];
    int f = (i4 & 31) * 4;
    v.x = fmaxf(fmaf(v.x, sc[f + 0], sh[f + 0]), 0.f);
    v.y = fmaxf(fmaf(v.y, sc[f + 1], sh[f + 1]), 0.f);
    v.z = fmaxf(fmaf(v.z, sc[f + 2], sh[f + 2]), 0.f);
    v.w = fmaxf(fmaf(v.w, sc[f + 3], sh[f + 3]), 0.f);
    ((float4*)out)[i4] = v;
  }
}

extern "C" void kernel_launch(void* const* d_in, const int* in_sizes, int n_in,
                              void* d_out, int out_size, void* d_ws, size_t ws_size,
                              hipStream_t stream) {
  const float* x   = (const float*)d_in[0];
  const int*   ei  = (const int*)d_in[1];
  const float* W1  = (const float*)d_in[2];
  const float* b1  = (const float*)d_in[3];
  const float* g1  = (const float*)d_in[4];
  const float* be1 = (const float*)d_in[5];
  const float* Wl  = (const float*)d_in[6];
  const float* bl  = (const float*)d_in[7];
  const float* Wr  = (const float*)d_in[8];
  const float* g2  = (const float*)d_in[9];
  const float* be2 = (const float*)d_in[10];
  const int* srcp = ei;
  const int* dstp = ei + NE;

  char* w = (char*)d_ws;
  auto alloc = [&](size_t bytes) {
    char* p = w;
    w += (bytes + 255) & ~(size_t)255;
    return p;
  };
  // single zeroed zone: cnt[NN] | slotted stats 4 x [32][128]
  size_t zbytes = ((size_t)NN + 4 * NSLOT * 128) * 4;
  char* zz = (char*)alloc(zbytes);
  int*   cnt   = (int*)zz;
  float* stats = (float*)(cnt + NN);
  float* sums1s = stats,                     *sumsq1s = stats + NSLOT * 128;
  float* sums2s = stats + 2 * NSLOT * 128,   *sumsq2s = stats + 3 * NSLOT * 128;

  int*   csr = (int*)alloc((size_t)NN * CAP * 4);  // 12.8 MB strided buckets
  unsigned short* xs = (unsigned short*)alloc((size_t)NN * FIN * 2);
  unsigned short* hb = (unsigned short*)alloc((size_t)NN * FHID * 2);
  short* Wp1 = (short*)alloc(8192 * 2);
  short* Wp2 = (short*)alloc(32768 * 2);

  hipMemsetAsync(zz, 0, zbytes, stream);

  int nbE4 = (NE / 4 + 255) / 256;        // 586 edge blocks
  int nbW  = (8192 + 32768 + 255) / 256;  // 160 weight-pack blocks
  int nb16 = NN / 16;                     // 3125 fused agg+GEMM blocks

  // 1: CSR build + weight packing (independent block ranges)
  bucket_fill<<<nbE4 + nbW, 256, 0, stream>>>(srcp, dstp, cnt, csr, W1, Wl, Wr,
                                              Wp1, Wp2, nbE4);
  // 2: prescale + bucket pad
  scale_x<<<NN * FIN / 4 / 256, 256, 0, stream>>>(x, cnt, (ushort4*)xs, csr);
  // 3: GCN agg (1 node / 16-lane group) + K=64 MFMA -> raw bf16 hb + stats1
  gcn_block<<<nb16, 256, 0, stream>>>(xs, csr, cnt, Wp1, b1, hb, sums1s, sumsq1s);
  // 4: BN1 finalize + apply + ReLU in place on hb
  bn_slot_apply_bf<<<512, 256, 0, stream>>>((unsigned*)hb, sums1s, sumsq1s, g1, be1);
  // 5: SAGE plain-add mean-agg + K=256 MFMA -> fp32 out + stats2
  sage_block<<<nb16, 256, 0, stream>>>(hb, csr, cnt, Wp2, bl, (float*)d_out,
                                       sums2s, sumsq2s);
  // 6: BN2 finalize + apply + ReLU
  bn_slot_apply_f32<<<512, 256, 0, stream>>>((float*)d_out, sums2s, sumsq2s, g2, be2);
}